// Round 2
// baseline (243.995 us; speedup 1.0000x reference)
//
#include <hip/hip_runtime.h>
#include <math.h>

#define EPS 1e-5f
#define T_LEN 8192
#define ROWS_PER_BLOCK 8

// XOR swizzle on 16B-granule index: involution, permutes granules only
// within their aligned 128B group (low 3 bits XOR'ed with bits 3..5).
__device__ __forceinline__ int swz(int a) { return a ^ ((a >> 3) & 7); }

// One block = 8 consecutive rows, 512 threads (8 waves), 2-row LDS double
// buffer (64 KB -> 2 blocks/CU). Software pipeline with counted vmcnt:
//   iter r: issue DMA(row r+1, buf^1)           [4 global_load_lds / wave]
//           s_waitcnt vmcnt(4)  <- row r's DMA done, row r+1's stays in flight
//           s_barrier
//           ds_read own 16 elems, block scan, replay-normalize in registers,
//           store straight to global (each thread owns a 64B sector).
// No __syncthreads anywhere -> vmcnt never drains to 0 in the loop.
// 1/count is row-invariant: precomputed per-thread rcp table (16 regs).
__global__ __launch_bounds__(512, 2) void causal_ln_kernel(
    const float* __restrict__ x,
    const float* __restrict__ weight,
    const float* __restrict__ bias,
    float* __restrict__ out,
    int C, int T)
{
    __shared__ float lds[2][T_LEN];      // 2 x 32 KB
    __shared__ float wsum[8], wsum2[8];

    const int t    = threadIdx.x;        // 0..511
    const int lane = t & 63;
    const int wid  = t >> 6;             // wave id 0..7
    const int row0 = blockIdx.x * ROWS_PER_BLOCK;

    // per-thread 1/count table: counts t*16+1 .. t*16+16 (row-invariant)
    float rc[16];
#pragma unroll
    for (int k = 0; k < 16; ++k)
        rc[k] = __builtin_amdgcn_rcpf((float)(t * 16 + k + 1));

    // ---- stage row r into LDS buffer b (async DMA, pre-swizzled src) ----
    auto stage = [&](int b, int r) {
        const float* xrow = x + (long long)(row0 + r) * (long long)T_LEN;
#pragma unroll
        for (int j = 0; j < 4; ++j) {
            int slot = j * 512 + t;      // linear LDS granule this lane fills
            int g    = swz(slot);        // global granule landing here
            const __attribute__((address_space(1))) float* gp =
                (const __attribute__((address_space(1))) float*)(xrow + g * 4);
            __attribute__((address_space(3))) float* lp =
                (__attribute__((address_space(3))) float*)
                    (&lds[b][(j * 512 + (wid << 6)) * 4]);
            __builtin_amdgcn_global_load_lds(gp, lp, 16, 0, 0);
        }
    };

    stage(0, 0);                         // prologue: row 0 in flight

    for (int r = 0; r < ROWS_PER_BLOCK; ++r) {
        const int cur = r & 1;
        if (r + 1 < ROWS_PER_BLOCK)
            stage(cur ^ 1, r + 1);       // prefetch next row (stays in flight)

        // wait for row r's 4 DMA instrs only (oldest); prefetch + old stores
        // may remain outstanding.
        asm volatile("s_waitcnt vmcnt(4)" ::: "memory");
        __builtin_amdgcn_s_barrier();    // all waves' row-r DMA visible

        // ---- own 16 contiguous elements from swizzled slots ----
        float4 v[4];
#pragma unroll
        for (int j = 0; j < 4; ++j)
            v[j] = *(const float4*)&lds[cur][swz(t * 4 + j) * 4];

        float s = 0.f, s2 = 0.f;
#pragma unroll
        for (int j = 0; j < 4; ++j) {
            s  += v[j].x + v[j].y + v[j].z + v[j].w;
            s2 += v[j].x * v[j].x + v[j].y * v[j].y
                + v[j].z * v[j].z + v[j].w * v[j].w;
        }

        // wave64 inclusive scan of (s, s2)
        float ws = s, ws2 = s2;
#pragma unroll
        for (int off = 1; off < 64; off <<= 1) {
            float a  = __shfl_up(ws,  off, 64);
            float a2 = __shfl_up(ws2, off, 64);
            if (lane >= off) { ws += a; ws2 += a2; }
        }

        // cross-wave combine (8 waves) — raw barrier + manual lgkm drain
        if (lane == 63) { wsum[wid] = ws; wsum2[wid] = ws2; }
        asm volatile("s_waitcnt lgkmcnt(0)" ::: "memory");
        __builtin_amdgcn_s_barrier();

        float off1 = 0.f, off2 = 0.f;
#pragma unroll
        for (int k = 0; k < 8; ++k) {
            if (k < wid) { off1 += wsum[k]; off2 += wsum2[k]; }
        }

        float es  = __shfl_up(ws,  1, 64);
        float es2 = __shfl_up(ws2, 1, 64);
        if (lane == 0) { es = 0.f; es2 = 0.f; }
        float run  = off1 + es;
        float run2 = off2 + es2;

        const int   row = row0 + r;
        const float wv  = weight[row % C];
        const float bv  = bias[row % C];

        // ---- replay, normalize in registers, store direct ----
        float4 o[4];
#pragma unroll
        for (int j = 0; j < 4; ++j) {
            float xs[4] = {v[j].x, v[j].y, v[j].z, v[j].w};
#pragma unroll
            for (int i = 0; i < 4; ++i) {
                float xi = xs[i];
                run  += xi;
                run2 += xi * xi;
                float rcv  = rc[j * 4 + i];
                float mean = run * rcv;
                float var  = fmaxf(run2 * rcv - mean * mean, 0.f);
                float rinv = __builtin_amdgcn_rsqf(var + EPS);
                xs[i] = (xi - mean) * rinv * wv + bv;
            }
            o[j] = make_float4(xs[0], xs[1], xs[2], xs[3]);
        }

        float4* og = (float4*)(out + (long long)row * (long long)T_LEN + t * 16);
#pragma unroll
        for (int j = 0; j < 4; ++j)
            og[j] = o[j];
    }
}

extern "C" void kernel_launch(void* const* d_in, const int* in_sizes, int n_in,
                              void* d_out, int out_size, void* d_ws, size_t ws_size,
                              hipStream_t stream) {
    const float* x      = (const float*)d_in[0];
    const float* weight = (const float*)d_in[1];
    const float* bias   = (const float*)d_in[2];
    float* out          = (float*)d_out;

    const int C = in_sizes[1];            // 512 (weight is [1,C,1])
    const int T = 8192;                   // time length per row
    const int rows = in_sizes[0] / T;     // B*C = 4096

    dim3 grid(rows / ROWS_PER_BLOCK), block(512);
    hipLaunchKernelGGL(causal_ln_kernel, grid, block, 0, stream,
                       x, weight, bias, out, C, T);
}

// Round 3
// 234.381 us; speedup vs baseline: 1.0410x; 1.0410x over previous
//
#include <hip/hip_runtime.h>
#include <math.h>

#define EPS 1e-5f
#define T_LEN 8192

// One block = one (b,c) row. 512 threads, 8 waves. NO data staging in LDS:
// thread t owns granule g = j*512 + t (4 consecutive floats) for j=0..3, so
// every global load/store instruction is lane-consecutive float4 (coalesced).
// Prefix over granules in (j,t)-lex order = row-major [4][512]:
//   prefix(j,t) = sum of full rows j' < j  (register running offset)
//              + cross-wave offset for row j (tiny LDS combine, one barrier)
//              + intra-wave exclusive scan for row j (shfl).
// Each thread then serially replays its 4 elements per granule in registers.
// Pure streaming kernel: latency hidden by TLP (independent blocks), not by
// software pipelining.
__global__ __launch_bounds__(512, 4) void causal_ln_kernel(
    const float* __restrict__ x,
    const float* __restrict__ weight,
    const float* __restrict__ bias,
    float* __restrict__ out,
    int C)
{
    __shared__ float4 wsumS[8], wsumQ[8];   // per-wave totals, per j-row

    const int t    = threadIdx.x;           // 0..511
    const int lane = t & 63;
    const int wid  = t >> 6;                // wave id 0..7
    const int row  = blockIdx.x;            // b*C + c

    // ---- coalesced loads straight to registers ----
    const float4* xg = (const float4*)(x + (long long)row * T_LEN);
    float4 v[4];
#pragma unroll
    for (int j = 0; j < 4; ++j)
        v[j] = xg[j * 512 + t];

    // per-granule (sum, sumsq)
    float gs[4], gq[4];
#pragma unroll
    for (int j = 0; j < 4; ++j) {
        gs[j] = v[j].x + v[j].y + v[j].z + v[j].w;
        gq[j] = v[j].x * v[j].x + v[j].y * v[j].y
              + v[j].z * v[j].z + v[j].w * v[j].w;
    }

    // ---- wave64 inclusive scan over t of the 4-vector (s, s2) ----
    float ws[4], wq[4];
#pragma unroll
    for (int j = 0; j < 4; ++j) { ws[j] = gs[j]; wq[j] = gq[j]; }
#pragma unroll
    for (int off = 1; off < 64; off <<= 1) {
#pragma unroll
        for (int j = 0; j < 4; ++j) {
            float a = __shfl_up(ws[j], off, 64);
            float b = __shfl_up(wq[j], off, 64);
            if (lane >= off) { ws[j] += a; wq[j] += b; }
        }
    }

    // ---- cross-wave combine: 8 float4s per quantity ----
    if (lane == 63) {
        wsumS[wid] = make_float4(ws[0], ws[1], ws[2], ws[3]);
        wsumQ[wid] = make_float4(wq[0], wq[1], wq[2], wq[3]);
    }
    __syncthreads();

    float woS[4] = {0.f,0.f,0.f,0.f}, woQ[4] = {0.f,0.f,0.f,0.f};  // waves < wid
    float rtS[4] = {0.f,0.f,0.f,0.f}, rtQ[4] = {0.f,0.f,0.f,0.f};  // row totals
#pragma unroll
    for (int w = 0; w < 8; ++w) {
        float4 a = wsumS[w], b = wsumQ[w];
        float am[4] = {a.x, a.y, a.z, a.w};
        float bm[4] = {b.x, b.y, b.z, b.w};
#pragma unroll
        for (int j = 0; j < 4; ++j) {
            rtS[j] += am[j]; rtQ[j] += bm[j];
            if (w < wid) { woS[j] += am[j]; woQ[j] += bm[j]; }
        }
    }

    // intra-wave exclusive = shift inclusive down by one lane (exact)
    float es[4], eq[4];
#pragma unroll
    for (int j = 0; j < 4; ++j) {
        es[j] = __shfl_up(ws[j], 1, 64);
        eq[j] = __shfl_up(wq[j], 1, 64);
    }
    if (lane == 0) {
#pragma unroll
        for (int j = 0; j < 4; ++j) { es[j] = 0.f; eq[j] = 0.f; }
    }

    const float wv = weight[row % C];
    const float bv = bias[row % C];
    float4* og = (float4*)(out + (long long)row * T_LEN);

    // ---- replay each granule, store coalesced ----
    float rp = 0.f, rq = 0.f;                 // sum of full j-rows before j
#pragma unroll
    for (int j = 0; j < 4; ++j) {
        float run  = rp + woS[j] + es[j];
        float run2 = rq + woQ[j] + eq[j];
        float cnt  = (float)(4 * (j * 512 + t));   // elements before granule
        float xs[4] = {v[j].x, v[j].y, v[j].z, v[j].w};
#pragma unroll
        for (int i = 0; i < 4; ++i) {
            float xi = xs[i];
            run  += xi;
            run2 += xi * xi;
            cnt  += 1.f;
            float rcv  = __builtin_amdgcn_rcpf(cnt);
            float mean = run * rcv;
            float var  = fmaxf(run2 * rcv - mean * mean, 0.f);
            float rinv = __builtin_amdgcn_rsqf(var + EPS);
            xs[i] = (xi - mean) * rinv * wv + bv;
        }
        og[j * 512 + t] = make_float4(xs[0], xs[1], xs[2], xs[3]);
        rp += rtS[j]; rq += rtQ[j];
    }
}

extern "C" void kernel_launch(void* const* d_in, const int* in_sizes, int n_in,
                              void* d_out, int out_size, void* d_ws, size_t ws_size,
                              hipStream_t stream) {
    const float* x      = (const float*)d_in[0];
    const float* weight = (const float*)d_in[1];
    const float* bias   = (const float*)d_in[2];
    float* out          = (float*)d_out;

    const int C = in_sizes[1];            // 512 (weight is [1,C,1])
    const int T = 8192;                   // time length per row
    const int rows = in_sizes[0] / T;     // B*C = 4096

    dim3 grid(rows), block(512);
    hipLaunchKernelGGL(causal_ln_kernel, grid, block, 0, stream,
                       x, weight, bias, out, C);
}